// Round 2
// baseline (2731.515 us; speedup 1.0000x reference)
//
#include <hip/hip_runtime.h>
#include <math.h>

#define BB 4
#define SS 4096
#define HH 2048
#define HF 14336      // 7*H
#define RR 64
#define NUU 131072    // H*RR
#define N1 1024
#define N2 512
#define N3 256
#define NCHUNK 32
#define CHUNKS 128    // SS / NCHUNK
#define MM (BB * SS)  // 16384 rows

#define NEG_INF -3.402823466e38f

typedef unsigned short ushort_t;
typedef __attribute__((ext_vector_type(8))) short short8v;
typedef __attribute__((ext_vector_type(4))) float f32x4;

__device__ inline ushort_t f2bf(float f) {
  union { float f; unsigned u; } c; c.f = f;
  unsigned r = (c.u + 0x7fffu + ((c.u >> 16) & 1u)) >> 16;
  return (ushort_t)r;
}
__device__ inline float bf2f(ushort_t h) {
  union { unsigned u; float f; } c; c.u = ((unsigned)h) << 16;
  return c.f;
}

// ---------------- row norms ----------------
__global__ __launch_bounds__(256) void rownorm_kernel(const float* __restrict__ x,
                                                      float* __restrict__ norms) {
  int row = blockIdx.x, t = threadIdx.x;
  const float4* p = (const float4*)(x + (size_t)row * HH);
  float4 a = p[t], b = p[t + 256];
  float s = a.x * a.x + a.y * a.y + a.z * a.z + a.w * a.w
          + b.x * b.x + b.y * b.y + b.z * b.z + b.w * b.w;
#pragma unroll
  for (int o = 32; o > 0; o >>= 1) s += __shfl_down(s, o, 64);
  __shared__ float sm[4];
  if ((t & 63) == 0) sm[t >> 6] = s;
  __syncthreads();
  if (t == 0) norms[row] = sqrtf(sm[0] + sm[1] + sm[2] + sm[3]);
}

// ---------------- nrm feature ----------------
__global__ __launch_bounds__(256) void nrm_reduce_kernel(const float* __restrict__ norms,
                                                         float* __restrict__ feats) {
  int b = blockIdx.x, t = threadIdx.x;
  float s = 0.f;
  for (int i = t; i < SS; i += 256) s += norms[b * SS + i];
#pragma unroll
  for (int o = 32; o > 0; o >>= 1) s += __shfl_down(s, o, 64);
  __shared__ float sm[4];
  __shared__ float meansh;
  if ((t & 63) == 0) sm[t >> 6] = s;
  __syncthreads();
  if (t == 0) meansh = (sm[0] + sm[1] + sm[2] + sm[3]) / (float)SS;
  __syncthreads();
  float m = meansh;
  for (int h = t; h < HH; h += 256) feats[(size_t)b * HF + 2 * HH + h] = m;
}

// ---------------- moment partials + x -> (xh, xl) bf16 split ----------------
__global__ __launch_bounds__(256) void stats_convert_kernel(const float* __restrict__ x,
                                                            float* __restrict__ part,
                                                            ushort_t* __restrict__ xh,
                                                            ushort_t* __restrict__ xl) {
  int t = threadIdx.x;
  int h = blockIdx.x * 256 + t;
  int y = blockIdx.y;
  int b = y >> 5, c = y & 31;
  size_t base = ((size_t)(b * SS + c * CHUNKS)) * HH + h;
  float s1 = 0.f, s2 = 0.f, s3 = 0.f, s4 = 0.f, mx = NEG_INF, mn = -NEG_INF;
  for (int i = 0; i < CHUNKS; ++i) {
    size_t gi = base + (size_t)i * HH;
    float v = x[gi];
    ushort_t hb = f2bf(v);
    xh[gi] = hb;
    xl[gi] = f2bf(v - bf2f(hb));
    s1 += v;
    float v2 = v * v;
    s2 += v2; s3 += v2 * v; s4 += v2 * v2;
    mx = fmaxf(mx, v); mn = fminf(mn, v);
  }
  float* o = part + ((size_t)y * 6) * HH + h;
  o[0] = s1; o[HH] = s2; o[2 * HH] = s3; o[3 * HH] = s4; o[4 * HH] = mx; o[5 * HH] = mn;
}

// ---------------- combine partials (fp64) ----------------
__global__ __launch_bounds__(256) void moment_reduce_kernel(const float* __restrict__ part,
                                                            float* __restrict__ feats) {
  int t = threadIdx.x;
  int h = blockIdx.x * 256 + t;
  int b = blockIdx.y;
  double S1 = 0, S2 = 0, S3 = 0, S4 = 0;
  float mx = NEG_INF, mn = -NEG_INF;
  for (int c = 0; c < NCHUNK; ++c) {
    const float* o = part + ((size_t)(b * NCHUNK + c) * 6) * HH + h;
    S1 += (double)o[0]; S2 += (double)o[HH]; S3 += (double)o[2 * HH]; S4 += (double)o[3 * HH];
    mx = fmaxf(mx, o[4 * HH]); mn = fminf(mn, o[5 * HH]);
  }
  const double n = (double)SS;
  double m = S1 / n;
  double varu = (S2 - n * m * m) / (n - 1.0);
  if (varu < 0.0) varu = 0.0;
  double sd = sqrt(varu);
  double c3 = (S3 - 3.0 * m * S2 + 2.0 * n * m * m * m) / n;
  double c4 = (S4 - 4.0 * m * S3 + 6.0 * m * m * S2 - 3.0 * n * m * m * m * m) / n;
  double skew = c3 / (sd * sd * sd + 1e-8);
  double kurt = c4 / (sd * sd * sd * sd + 1e-8) - 3.0;
  float* f = feats + (size_t)b * HF;
  f[0 * HH + h] = (float)m;
  f[1 * HH + h] = (float)sd;
  f[3 * HH + h] = mx;
  f[4 * HH + h] = mn;
  f[5 * HH + h] = (float)skew;
  f[6 * HH + h] = (float)kurt;
}

// ---------------- skinny GEMM (split-K atomics) ----------------
__global__ __launch_bounds__(256) void gemm_small_kernel(const float* __restrict__ A,
                                                         const float* __restrict__ W,
                                                         float* __restrict__ z,
                                                         int K, int N, int KC) {
  extern __shared__ float sa[];
  int t = threadIdx.x;
  int k0 = blockIdx.x * KC;
  for (int e = t; e < 4 * KC; e += 256) {
    int b = e / KC, k = e - b * KC;
    sa[b * KC + k] = A[(size_t)b * K + k0 + k];
  }
  __syncthreads();
  int n = blockIdx.y * 256 + t;
  float acc0 = 0.f, acc1 = 0.f, acc2 = 0.f, acc3 = 0.f;
  for (int k = 0; k < KC; ++k) {
    float w = W[(size_t)(k0 + k) * N + n];
    acc0 += sa[0 * KC + k] * w;
    acc1 += sa[1 * KC + k] * w;
    acc2 += sa[2 * KC + k] * w;
    acc3 += sa[3 * KC + k] * w;
  }
  atomicAdd(&z[0 * N + n], acc0);
  atomicAdd(&z[1 * N + n], acc1);
  atomicAdd(&z[2 * N + n], acc2);
  atomicAdd(&z[3 * N + n], acc3);
}

// ---------------- LayerNorm + bias + relu ----------------
__global__ __launch_bounds__(256) void ln_relu_kernel(const float* __restrict__ z,
                                                      const float* __restrict__ bias,
                                                      const float* __restrict__ g,
                                                      const float* __restrict__ beta,
                                                      float* __restrict__ out, int N) {
  int b = blockIdx.x, t = threadIdx.x;
  int per = N >> 8;
  float v[4];
  float s = 0.f, s2 = 0.f;
  for (int i = 0; i < per; ++i) {
    int idx = i * 256 + t;
    float val = z[b * N + idx] + bias[idx];
    v[i] = val; s += val; s2 += val * val;
  }
#pragma unroll
  for (int o = 32; o > 0; o >>= 1) {
    s += __shfl_down(s, o, 64);
    s2 += __shfl_down(s2, o, 64);
  }
  __shared__ float sm[8];
  if ((t & 63) == 0) { sm[t >> 6] = s; sm[4 + (t >> 6)] = s2; }
  __syncthreads();
  __shared__ float musm, varsm;
  if (t == 0) {
    float ts = sm[0] + sm[1] + sm[2] + sm[3];
    float ts2 = sm[4] + sm[5] + sm[6] + sm[7];
    float mu = ts / (float)N;
    musm = mu;
    varsm = ts2 / (float)N - mu * mu;
  }
  __syncthreads();
  float mu = musm;
  float rs = rsqrtf(varsm + 1e-5f);
  for (int i = 0; i < per; ++i) {
    int idx = i * 256 + t;
    float y = (v[i] - mu) * rs * g[idx] + beta[idx];
    out[b * N + idx] = fmaxf(y, 0.f);
  }
}

// ---------------- h3 = relu(z3 + b3) ----------------
__global__ __launch_bounds__(256) void bias_relu3_kernel(const float* __restrict__ z3,
                                                         const float* __restrict__ b3,
                                                         float* __restrict__ h3) {
  int t = threadIdx.x;
  for (int b = 0; b < 4; ++b) h3[b * N3 + t] = fmaxf(z3[b * N3 + t] + b3[t], 0.f);
}

// ---------------- U fp32; V -> w2-scaled transposed bf16 splits ----------------
__global__ __launch_bounds__(256) void uv_kernel(const float* __restrict__ h3,
                                                 const float* __restrict__ Wu,
                                                 const float* __restrict__ bu,
                                                 const float* __restrict__ su,
                                                 const float* __restrict__ Wv,
                                                 const float* __restrict__ bv,
                                                 const float* __restrict__ sv,
                                                 const float* __restrict__ rwp,
                                                 float* __restrict__ U,
                                                 ushort_t* __restrict__ VhT,
                                                 ushort_t* __restrict__ VlT) {
  int which = blockIdx.y;
  const float* W = which ? Wv : Wu;
  const float* bias = which ? bv : bu;
  const float* sc = which ? sv : su;
  __shared__ float hs[4][N3];
  int t = threadIdx.x;
  for (int b = 0; b < 4; ++b) hs[b][t] = h3[b * N3 + t];
  __syncthreads();
  size_t n = (size_t)blockIdx.x * 256 + t;
  float a0 = 0.f, a1 = 0.f, a2 = 0.f, a3 = 0.f;
  for (int k = 0; k < N3; ++k) {
    float w = W[(size_t)k * NUU + n];
    a0 += hs[0][k] * w; a1 += hs[1][k] * w; a2 += hs[2][k] * w; a3 += hs[3][k] * w;
  }
  float s = *sc;
  float bb = bias[n];
  float r0 = (a0 + bb) * s, r1 = (a1 + bb) * s, r2 = (a2 + bb) * s, r3 = (a3 + bb) * s;
  if (!which) {
    U[0 * (size_t)NUU + n] = r0;
    U[1 * (size_t)NUU + n] = r1;
    U[2 * (size_t)NUU + n] = r2;
    U[3 * (size_t)NUU + n] = r3;
  } else {
    float w2 = 1.f - *rwp;
    int kr = (int)(n >> 11);       // rank index
    int hcol = (int)(n & 2047);    // output column
    size_t o = (size_t)hcol * RR + kr;
    float vals[4] = {r0 * w2, r1 * w2, r2 * w2, r3 * w2};
#pragma unroll
    for (int b = 0; b < 4; ++b) {
      ushort_t hb = f2bf(vals[b]);
      VhT[(size_t)b * NUU + o] = hb;
      VlT[(size_t)b * NUU + o] = f2bf(vals[b] - bf2f(hb));
    }
  }
}

// ---------------- transpose + split rw*Base -> BhT, BlT ----------------
__global__ __launch_bounds__(256) void convert_base_kernel(const float* __restrict__ Bse,
                                                           const float* __restrict__ rwp,
                                                           ushort_t* __restrict__ BhT,
                                                           ushort_t* __restrict__ BlT) {
  __shared__ float tl[64][65];
  int t = threadIdx.x;
  int k0 = blockIdx.x * 64, n0 = blockIdx.y * 64;
  float rw = *rwp;
#pragma unroll
  for (int j = 0; j < 16; ++j) {
    int idx = j * 256 + t; int r = idx >> 6, c = idx & 63;
    tl[r][c] = Bse[(size_t)(k0 + r) * HH + n0 + c];
  }
  __syncthreads();
#pragma unroll
  for (int j = 0; j < 16; ++j) {
    int idx = j * 256 + t; int r = idx >> 6, c = idx & 63;  // r: n, c: k
    float v = rw * tl[c][r];
    ushort_t hb = f2bf(v);
    size_t o = (size_t)(n0 + r) * HH + k0 + c;
    BhT[o] = hb;
    BlT[o] = f2bf(v - bf2f(hb));
  }
}

// ---------------- P = x @ U (fp32), emit bf16 splits Ph, Pl ----------------
__global__ __launch_bounds__(256) void p_gemm_kernel(const float* __restrict__ x,
                                                     const float* __restrict__ U,
                                                     ushort_t* __restrict__ Ph,
                                                     ushort_t* __restrict__ Pl) {
  __shared__ __align__(16) float as[64][68];
  __shared__ __align__(16) float bs[64][64];
  int t = threadIdx.x;
  int row0 = blockIdx.x * 64;
  int b = row0 >> 12;
  int tr = t & 15, trow = t >> 4;
  float acc[4][4] = {};
  for (int kc = 0; kc < 32; ++kc) {
#pragma unroll
    for (int i = 0; i < 16; ++i) {
      int e = i * 256 + t;
      int r = e >> 6, c = e & 63;
      as[r][c] = x[(size_t)(row0 + r) * HH + kc * 64 + c];
      bs[r][c] = U[(size_t)b * NUU + (size_t)(kc * 64 + r) * 64 + c];
    }
    __syncthreads();
#pragma unroll
    for (int g = 0; g < 16; ++g) {
      float4 xv[4], uv[4];
#pragma unroll
      for (int i = 0; i < 4; ++i) xv[i] = *(const float4*)&as[trow * 4 + i][g * 4];
#pragma unroll
      for (int j = 0; j < 4; ++j) uv[j] = *(const float4*)&bs[g * 4 + j][tr * 4];
#pragma unroll
      for (int h = 0; h < 4; ++h)
#pragma unroll
        for (int i = 0; i < 4; ++i) {
          float a = ((const float*)&xv[i])[h];
#pragma unroll
          for (int j = 0; j < 4; ++j) acc[i][j] += a * ((const float*)&uv[h])[j];
        }
    }
    __syncthreads();
  }
#pragma unroll
  for (int i = 0; i < 4; ++i) {
#pragma unroll
    for (int j = 0; j < 4; ++j) {
      float v = acc[i][j];
      ushort_t hb = f2bf(v);
      size_t o = (size_t)(row0 + trow * 4 + i) * RR + tr * 4 + j;
      Ph[o] = hb;
      Pl[o] = f2bf(v - bf2f(hb));
    }
  }
}

// ---------------- main MFMA GEMM: out = [xh|xl|xh|Ph|Ph|Pl] @ [Bh;Bh;Bl;Vh;Vl;Vh] ----------------
// 128x128 tile, BK=64 bf16, 4 waves (2x2), 99 k-tiles (96 Base-part + 3 lowrank-part).
__global__ __launch_bounds__(256, 2) void gemm_mfma_kernel(
    const ushort_t* __restrict__ xh, const ushort_t* __restrict__ xl,
    const ushort_t* __restrict__ BhT, const ushort_t* __restrict__ BlT,
    const ushort_t* __restrict__ Ph, const ushort_t* __restrict__ Pl,
    const ushort_t* __restrict__ VhT, const ushort_t* __restrict__ VlT,
    float* __restrict__ out) {
  __shared__ __align__(16) char smem[32768];
  char* ldsA = smem;
  char* ldsB = smem + 16384;

  const int t = threadIdx.x;
  const int lane = t & 63;
  const int wid = t >> 6;
  const int wr = wid >> 1, wc = wid & 1;
  const int row0 = blockIdx.x * 128;
  const int n0 = blockIdx.y * 128;
  const int bidx = row0 >> 12;  // batch of this row-panel (128 | 4096)

  // staging geometry: 4 chunks of 16B per thread per tile
  int rr[4], cc[4], wa[4];
#pragma unroll
  for (int i = 0; i < 4; ++i) {
    int L = (i * 256 + t) * 16;          // linear byte in 16KB tile
    rr[i] = L >> 7;                      // tile row (0..127)
    cc[i] = L & 127;                     // byte col (0..127)
    wa[i] = (rr[i] << 7) + (cc[i] ^ ((rr[i] & 7) << 4));  // swizzled LDS byte addr
  }

  float4 areg[4], breg[4];

  auto load_tiles = [&](int kt) {
    const char* Ab; const char* Bb; size_t asb, bsb;
    if (kt < 96) {
      int kc = (kt & 31) << 6;
      const ushort_t* Am = (kt < 32) ? xh : (kt < 64) ? xl : xh;
      Ab = (const char*)(Am + (size_t)row0 * HH + kc); asb = HH * 2;
      const ushort_t* Bm = (kt < 64) ? BhT : BlT;
      Bb = (const char*)(Bm + (size_t)n0 * HH + kc); bsb = HH * 2;
    } else {
      const ushort_t* Am = (kt == 98) ? Pl : Ph;
      Ab = (const char*)(Am + (size_t)row0 * RR); asb = RR * 2;
      const ushort_t* Bm = (kt == 97) ? VlT : VhT;
      Bb = (const char*)(Bm + (size_t)bidx * NUU + (size_t)n0 * RR); bsb = RR * 2;
    }
#pragma unroll
    for (int i = 0; i < 4; ++i) {
      areg[i] = *(const float4*)(Ab + (size_t)rr[i] * asb + cc[i]);
      breg[i] = *(const float4*)(Bb + (size_t)rr[i] * bsb + cc[i]);
    }
  };

  f32x4 acc[4][4] = {};

  load_tiles(0);
  for (int kt = 0; kt < 99; ++kt) {
    __syncthreads();  // all waves finished reading LDS of previous tile
#pragma unroll
    for (int i = 0; i < 4; ++i) {
      *(float4*)(ldsA + wa[i]) = areg[i];
      *(float4*)(ldsB + wa[i]) = breg[i];
    }
    if (kt + 1 < 99) load_tiles(kt + 1);  // prefetch next tile into regs (hidden under MFMA)
    __syncthreads();  // tile visible

    const int lg = (lane >> 4) << 4;       // k-group byte offset (0,16,32,48)
    const int sw = (lane & 7) << 4;        // row-dependent XOR (row&7 == lane&7 here)
    const int arow = (wr << 6) + (lane & 15);
    const int brow = (wc << 6) + (lane & 15);
#pragma unroll
    for (int ks = 0; ks < 2; ++ks) {
      short8v a_frag[4], b_frag[4];
      int cb = (ks << 6) + lg;
#pragma unroll
      for (int mi = 0; mi < 4; ++mi)
        a_frag[mi] = *(const short8v*)(ldsA + ((arow + (mi << 4)) << 7) + (cb ^ sw));
#pragma unroll
      for (int ni = 0; ni < 4; ++ni)
        b_frag[ni] = *(const short8v*)(ldsB + ((brow + (ni << 4)) << 7) + (cb ^ sw));
#pragma unroll
      for (int mi = 0; mi < 4; ++mi)
#pragma unroll
        for (int ni = 0; ni < 4; ++ni)
          acc[mi][ni] = __builtin_amdgcn_mfma_f32_16x16x32_bf16(
              a_frag[mi], b_frag[ni], acc[mi][ni], 0, 0, 0);
    }
  }

  // C write: D(row,col) at lane: col = lane&15, row = (lane>>4)*4 + j  [m89-verified]
  const int crow = row0 + (wr << 6) + ((lane >> 4) << 2);
  const int ccol = n0 + (wc << 6) + (lane & 15);
#pragma unroll
  for (int mi = 0; mi < 4; ++mi)
#pragma unroll
    for (int ni = 0; ni < 4; ++ni)
#pragma unroll
      for (int j = 0; j < 4; ++j)
        out[(size_t)(crow + (mi << 4) + j) * HH + ccol + (ni << 4)] = acc[mi][ni][j];
}

extern "C" void kernel_launch(void* const* d_in, const int* in_sizes, int n_in,
                              void* d_out, int out_size, void* d_ws, size_t ws_size,
                              hipStream_t stream) {
  const float* x = (const float*)d_in[0];
  const float* W1 = (const float*)d_in[1];
  const float* b1 = (const float*)d_in[2];
  const float* g1 = (const float*)d_in[3];
  const float* beta1 = (const float*)d_in[4];
  const float* W2 = (const float*)d_in[5];
  const float* b2 = (const float*)d_in[6];
  const float* g2 = (const float*)d_in[7];
  const float* beta2 = (const float*)d_in[8];
  const float* W3 = (const float*)d_in[9];
  const float* b3 = (const float*)d_in[10];
  const float* Wu = (const float*)d_in[11];
  const float* bu = (const float*)d_in[12];
  const float* Wv = (const float*)d_in[13];
  const float* bv = (const float*)d_in[14];
  const float* su = (const float*)d_in[15];
  const float* sv = (const float*)d_in[16];
  const float* rw = (const float*)d_in[17];
  const float* Bse = (const float*)d_in[18];
  float* out = (float*)d_out;

  char* w = (char*)d_ws;
  size_t off = 0;
  auto alloc = [&](size_t bytes) { char* p = w + off; off += (bytes + 255) & ~(size_t)255; return p; };

  float* norms = (float*)alloc((size_t)BB * SS * 4);
  float* zbuf  = (float*)alloc((size_t)BB * (N1 + N2 + N3) * 4);
  float* z1 = zbuf, *z2 = zbuf + BB * N1, *z3 = z2 + BB * N2;
  float* feats = (float*)alloc((size_t)BB * HF * 4);
  float* h1 = (float*)alloc((size_t)BB * N1 * 4);
  float* h2 = (float*)alloc((size_t)BB * N2 * 4);
  float* h3 = (float*)alloc((size_t)BB * N3 * 4);
  float* U  = (float*)alloc((size_t)BB * NUU * 4);
  float* part = (float*)alloc((size_t)BB * NCHUNK * 6 * HH * 4);
  ushort_t* xh  = (ushort_t*)alloc((size_t)MM * HH * 2);
  ushort_t* xl  = (ushort_t*)alloc((size_t)MM * HH * 2);
  ushort_t* BhT = (ushort_t*)alloc((size_t)HH * HH * 2);
  ushort_t* BlT = (ushort_t*)alloc((size_t)HH * HH * 2);
  ushort_t* Phb = (ushort_t*)alloc((size_t)MM * RR * 2);
  ushort_t* Plb = (ushort_t*)alloc((size_t)MM * RR * 2);
  ushort_t* VhT = (ushort_t*)alloc((size_t)BB * NUU * 2);
  ushort_t* VlT = (ushort_t*)alloc((size_t)BB * NUU * 2);

  hipMemsetAsync(zbuf, 0, (size_t)BB * (N1 + N2 + N3) * sizeof(float), stream);

  // stats + conversions (independent of MLP)
  rownorm_kernel<<<BB * SS, 256, 0, stream>>>(x, norms);
  stats_convert_kernel<<<dim3(HH / 256, BB * NCHUNK), 256, 0, stream>>>(x, part, xh, xl);
  moment_reduce_kernel<<<dim3(HH / 256, BB), 256, 0, stream>>>(part, feats);
  nrm_reduce_kernel<<<BB, 256, 0, stream>>>(norms, feats);
  convert_base_kernel<<<dim3(HH / 64, HH / 64), 256, 0, stream>>>(Bse, rw, BhT, BlT);

  // MLP
  gemm_small_kernel<<<dim3(HF / 512, N1 / 256), 256, 4 * 512 * sizeof(float), stream>>>(
      feats, W1, z1, HF, N1, 512);
  ln_relu_kernel<<<BB, 256, 0, stream>>>(z1, b1, g1, beta1, h1, N1);
  gemm_small_kernel<<<dim3(N1 / 512, N2 / 256), 256, 4 * 512 * sizeof(float), stream>>>(
      h1, W2, z2, N1, N2, 512);
  ln_relu_kernel<<<BB, 256, 0, stream>>>(z2, b2, g2, beta2, h2, N2);
  gemm_small_kernel<<<dim3(N2 / 256, N3 / 256), 256, 4 * 256 * sizeof(float), stream>>>(
      h2, W3, z3, N2, N3, 256);
  bias_relu3_kernel<<<1, 256, 0, stream>>>(z3, b3, h3);

  // U (fp32) and w2-scaled V^T bf16 splits
  uv_kernel<<<dim3(NUU / 256, 2), 256, 0, stream>>>(h3, Wu, bu, su, Wv, bv, sv, rw, U, VhT, VlT);

  // P = x @ U  -> bf16 splits
  p_gemm_kernel<<<BB * SS / 64, 256, 0, stream>>>(x, U, Phb, Plb);

  // one fused MFMA GEMM: out = rw*x@Base + (1-rw)*(x@U)@V
  gemm_mfma_kernel<<<dim3(MM / 128, HH / 128), 256, 0, stream>>>(
      xh, xl, BhT, BlT, Phb, Plb, VhT, VlT, out);
}

// Round 3
// 1139.089 us; speedup vs baseline: 2.3980x; 2.3980x over previous
//
#include <hip/hip_runtime.h>
#include <math.h>

#define BB 4
#define SS 4096
#define HH 2048
#define HF 14336      // 7*H
#define RR 64
#define NUU 131072    // H*RR
#define N1 1024
#define N2 512
#define N3 256
#define NCHUNK 32
#define CHUNKS 128    // SS / NCHUNK
#define MM (BB * SS)  // 16384 rows

#define NEG_INF -3.402823466e38f

typedef unsigned short ushort_t;
typedef __attribute__((ext_vector_type(8))) short short8v;
typedef __attribute__((ext_vector_type(4))) float f32x4;

// async global->LDS, 16B per lane, linear dest (wave-uniform base + lane*16)
#define GL16(g, l)                                                             \
  __builtin_amdgcn_global_load_lds(                                            \
      (const __attribute__((address_space(1))) void*)(g),                      \
      (__attribute__((address_space(3))) void*)(l), 16, 0, 0)

__device__ inline ushort_t f2bf(float f) {
  union { float f; unsigned u; } c; c.f = f;
  unsigned r = (c.u + 0x7fffu + ((c.u >> 16) & 1u)) >> 16;
  return (ushort_t)r;
}
__device__ inline float bf2f(ushort_t h) {
  union { unsigned u; float f; } c; c.u = ((unsigned)h) << 16;
  return c.f;
}

// ---------------- row norms ----------------
__global__ __launch_bounds__(256) void rownorm_kernel(const float* __restrict__ x,
                                                      float* __restrict__ norms) {
  int row = blockIdx.x, t = threadIdx.x;
  const float4* p = (const float4*)(x + (size_t)row * HH);
  float4 a = p[t], b = p[t + 256];
  float s = a.x * a.x + a.y * a.y + a.z * a.z + a.w * a.w
          + b.x * b.x + b.y * b.y + b.z * b.z + b.w * b.w;
#pragma unroll
  for (int o = 32; o > 0; o >>= 1) s += __shfl_down(s, o, 64);
  __shared__ float sm[4];
  if ((t & 63) == 0) sm[t >> 6] = s;
  __syncthreads();
  if (t == 0) norms[row] = sqrtf(sm[0] + sm[1] + sm[2] + sm[3]);
}

// ---------------- nrm feature ----------------
__global__ __launch_bounds__(256) void nrm_reduce_kernel(const float* __restrict__ norms,
                                                         float* __restrict__ feats) {
  int b = blockIdx.x, t = threadIdx.x;
  float s = 0.f;
  for (int i = t; i < SS; i += 256) s += norms[b * SS + i];
#pragma unroll
  for (int o = 32; o > 0; o >>= 1) s += __shfl_down(s, o, 64);
  __shared__ float sm[4];
  __shared__ float meansh;
  if ((t & 63) == 0) sm[t >> 6] = s;
  __syncthreads();
  if (t == 0) meansh = (sm[0] + sm[1] + sm[2] + sm[3]) / (float)SS;
  __syncthreads();
  float m = meansh;
  for (int h = t; h < HH; h += 256) feats[(size_t)b * HF + 2 * HH + h] = m;
}

// ---------------- moment partials + x -> (xh, xl) bf16 split ----------------
__global__ __launch_bounds__(256) void stats_convert_kernel(const float* __restrict__ x,
                                                            float* __restrict__ part,
                                                            ushort_t* __restrict__ xh,
                                                            ushort_t* __restrict__ xl) {
  int t = threadIdx.x;
  int h = blockIdx.x * 256 + t;
  int y = blockIdx.y;
  int b = y >> 5, c = y & 31;
  size_t base = ((size_t)(b * SS + c * CHUNKS)) * HH + h;
  float s1 = 0.f, s2 = 0.f, s3 = 0.f, s4 = 0.f, mx = NEG_INF, mn = -NEG_INF;
  for (int i = 0; i < CHUNKS; ++i) {
    size_t gi = base + (size_t)i * HH;
    float v = x[gi];
    ushort_t hb = f2bf(v);
    xh[gi] = hb;
    xl[gi] = f2bf(v - bf2f(hb));
    s1 += v;
    float v2 = v * v;
    s2 += v2; s3 += v2 * v; s4 += v2 * v2;
    mx = fmaxf(mx, v); mn = fminf(mn, v);
  }
  float* o = part + ((size_t)y * 6) * HH + h;
  o[0] = s1; o[HH] = s2; o[2 * HH] = s3; o[3 * HH] = s4; o[4 * HH] = mx; o[5 * HH] = mn;
}

// ---------------- combine partials (fp64) ----------------
__global__ __launch_bounds__(256) void moment_reduce_kernel(const float* __restrict__ part,
                                                            float* __restrict__ feats) {
  int t = threadIdx.x;
  int h = blockIdx.x * 256 + t;
  int b = blockIdx.y;
  double S1 = 0, S2 = 0, S3 = 0, S4 = 0;
  float mx = NEG_INF, mn = -NEG_INF;
  for (int c = 0; c < NCHUNK; ++c) {
    const float* o = part + ((size_t)(b * NCHUNK + c) * 6) * HH + h;
    S1 += (double)o[0]; S2 += (double)o[HH]; S3 += (double)o[2 * HH]; S4 += (double)o[3 * HH];
    mx = fmaxf(mx, o[4 * HH]); mn = fminf(mn, o[5 * HH]);
  }
  const double n = (double)SS;
  double m = S1 / n;
  double varu = (S2 - n * m * m) / (n - 1.0);
  if (varu < 0.0) varu = 0.0;
  double sd = sqrt(varu);
  double c3 = (S3 - 3.0 * m * S2 + 2.0 * n * m * m * m) / n;
  double c4 = (S4 - 4.0 * m * S3 + 6.0 * m * m * S2 - 3.0 * n * m * m * m * m) / n;
  double skew = c3 / (sd * sd * sd + 1e-8);
  double kurt = c4 / (sd * sd * sd * sd + 1e-8) - 3.0;
  float* f = feats + (size_t)b * HF;
  f[0 * HH + h] = (float)m;
  f[1 * HH + h] = (float)sd;
  f[3 * HH + h] = mx;
  f[4 * HH + h] = mn;
  f[5 * HH + h] = (float)skew;
  f[6 * HH + h] = (float)kurt;
}

// ---------------- skinny GEMM (split-K atomics) ----------------
__global__ __launch_bounds__(256) void gemm_small_kernel(const float* __restrict__ A,
                                                         const float* __restrict__ W,
                                                         float* __restrict__ z,
                                                         int K, int N, int KC) {
  extern __shared__ float sa[];
  int t = threadIdx.x;
  int k0 = blockIdx.x * KC;
  for (int e = t; e < 4 * KC; e += 256) {
    int b = e / KC, k = e - b * KC;
    sa[b * KC + k] = A[(size_t)b * K + k0 + k];
  }
  __syncthreads();
  int n = blockIdx.y * 256 + t;
  float acc0 = 0.f, acc1 = 0.f, acc2 = 0.f, acc3 = 0.f;
  for (int k = 0; k < KC; ++k) {
    float w = W[(size_t)(k0 + k) * N + n];
    acc0 += sa[0 * KC + k] * w;
    acc1 += sa[1 * KC + k] * w;
    acc2 += sa[2 * KC + k] * w;
    acc3 += sa[3 * KC + k] * w;
  }
  atomicAdd(&z[0 * N + n], acc0);
  atomicAdd(&z[1 * N + n], acc1);
  atomicAdd(&z[2 * N + n], acc2);
  atomicAdd(&z[3 * N + n], acc3);
}

// ---------------- LayerNorm + bias + relu ----------------
__global__ __launch_bounds__(256) void ln_relu_kernel(const float* __restrict__ z,
                                                      const float* __restrict__ bias,
                                                      const float* __restrict__ g,
                                                      const float* __restrict__ beta,
                                                      float* __restrict__ out, int N) {
  int b = blockIdx.x, t = threadIdx.x;
  int per = N >> 8;
  float v[4];
  float s = 0.f, s2 = 0.f;
  for (int i = 0; i < per; ++i) {
    int idx = i * 256 + t;
    float val = z[b * N + idx] + bias[idx];
    v[i] = val; s += val; s2 += val * val;
  }
#pragma unroll
  for (int o = 32; o > 0; o >>= 1) {
    s += __shfl_down(s, o, 64);
    s2 += __shfl_down(s2, o, 64);
  }
  __shared__ float sm[8];
  if ((t & 63) == 0) { sm[t >> 6] = s; sm[4 + (t >> 6)] = s2; }
  __syncthreads();
  __shared__ float musm, varsm;
  if (t == 0) {
    float ts = sm[0] + sm[1] + sm[2] + sm[3];
    float ts2 = sm[4] + sm[5] + sm[6] + sm[7];
    float mu = ts / (float)N;
    musm = mu;
    varsm = ts2 / (float)N - mu * mu;
  }
  __syncthreads();
  float mu = musm;
  float rs = rsqrtf(varsm + 1e-5f);
  for (int i = 0; i < per; ++i) {
    int idx = i * 256 + t;
    float y = (v[i] - mu) * rs * g[idx] + beta[idx];
    out[b * N + idx] = fmaxf(y, 0.f);
  }
}

// ---------------- h3 = relu(z3 + b3) ----------------
__global__ __launch_bounds__(256) void bias_relu3_kernel(const float* __restrict__ z3,
                                                         const float* __restrict__ b3,
                                                         float* __restrict__ h3) {
  int t = threadIdx.x;
  for (int b = 0; b < 4; ++b) h3[b * N3 + t] = fmaxf(z3[b * N3 + t] + b3[t], 0.f);
}

// ---------------- U -> UhT/UlT bf16 splits; V -> w2-scaled VhT/VlT bf16 splits ----------------
__global__ __launch_bounds__(256) void uv_kernel(const float* __restrict__ h3,
                                                 const float* __restrict__ Wu,
                                                 const float* __restrict__ bu,
                                                 const float* __restrict__ su,
                                                 const float* __restrict__ Wv,
                                                 const float* __restrict__ bv,
                                                 const float* __restrict__ sv,
                                                 const float* __restrict__ rwp,
                                                 ushort_t* __restrict__ UhT,
                                                 ushort_t* __restrict__ UlT,
                                                 ushort_t* __restrict__ VhT,
                                                 ushort_t* __restrict__ VlT) {
  int which = blockIdx.y;
  const float* W = which ? Wv : Wu;
  const float* bias = which ? bv : bu;
  const float* sc = which ? sv : su;
  __shared__ float hs[4][N3];
  int t = threadIdx.x;
  for (int b = 0; b < 4; ++b) hs[b][t] = h3[b * N3 + t];
  __syncthreads();
  size_t n = (size_t)blockIdx.x * 256 + t;
  float a0 = 0.f, a1 = 0.f, a2 = 0.f, a3 = 0.f;
  for (int k = 0; k < N3; ++k) {
    float w = W[(size_t)k * NUU + n];
    a0 += hs[0][k] * w; a1 += hs[1][k] * w; a2 += hs[2][k] * w; a3 += hs[3][k] * w;
  }
  float s = *sc;
  float bb = bias[n];
  float vals[4] = {(a0 + bb) * s, (a1 + bb) * s, (a2 + bb) * s, (a3 + bb) * s};
  if (!which) {
    // U[b][h][r], n = h*64+r  ->  UhT[b][r][h]
    int hh = (int)(n >> 6);
    int rr2 = (int)(n & 63);
    size_t o = (size_t)rr2 * HH + hh;
#pragma unroll
    for (int b = 0; b < 4; ++b) {
      ushort_t hb = f2bf(vals[b]);
      UhT[(size_t)b * NUU + o] = hb;
      UlT[(size_t)b * NUU + o] = f2bf(vals[b] - bf2f(hb));
    }
  } else {
    // V[b][r][h], n = r*2048+h -> w2-scaled VhT[b][h][r]
    float w2 = 1.f - *rwp;
    int kr = (int)(n >> 11);
    int hcol = (int)(n & 2047);
    size_t o = (size_t)hcol * RR + kr;
#pragma unroll
    for (int b = 0; b < 4; ++b) {
      float v = vals[b] * w2;
      ushort_t hb = f2bf(v);
      VhT[(size_t)b * NUU + o] = hb;
      VlT[(size_t)b * NUU + o] = f2bf(v - bf2f(hb));
    }
  }
}

// ---------------- transpose + split rw*Base -> BhT, BlT ----------------
__global__ __launch_bounds__(256) void convert_base_kernel(const float* __restrict__ Bse,
                                                           const float* __restrict__ rwp,
                                                           ushort_t* __restrict__ BhT,
                                                           ushort_t* __restrict__ BlT) {
  __shared__ float tl[64][65];
  int t = threadIdx.x;
  int k0 = blockIdx.x * 64, n0 = blockIdx.y * 64;
  float rw = *rwp;
#pragma unroll
  for (int j = 0; j < 16; ++j) {
    int idx = j * 256 + t; int r = idx >> 6, c = idx & 63;
    tl[r][c] = Bse[(size_t)(k0 + r) * HH + n0 + c];
  }
  __syncthreads();
#pragma unroll
  for (int j = 0; j < 16; ++j) {
    int idx = j * 256 + t; int r = idx >> 6, c = idx & 63;  // r: n, c: k
    float v = rw * tl[c][r];
    ushort_t hb = f2bf(v);
    size_t o = (size_t)(n0 + r) * HH + k0 + c;
    BhT[o] = hb;
    BlT[o] = f2bf(v - bf2f(hb));
  }
}

// ---------------- P = x @ U via MFMA (xh@Uh + xh@Ul + xl@Uh), emit Ph/Pl ----------------
// 128 rows x 64 cols per block, 2 waves (row-split), global_load_lds staging.
__global__ __launch_bounds__(128) void p_mfma_kernel(
    const ushort_t* __restrict__ xh, const ushort_t* __restrict__ xl,
    const ushort_t* __restrict__ UhT, const ushort_t* __restrict__ UlT,
    ushort_t* __restrict__ Ph, ushort_t* __restrict__ Pl) {
  __shared__ __align__(16) char smem[32768];
  char* ldsA = smem;            // 128 rows x 128B
  char* ldsB1 = smem + 16384;   // 64 rows x 128B
  char* ldsB2 = smem + 24576;
  const int t = threadIdx.x, lane = t & 63, w = t >> 6;
  const int row0 = blockIdx.x << 7;
  const int bidx = row0 >> 12;
  const int srow = (w << 3) + (lane >> 3);
  const int scb = ((lane & 7) ^ (lane >> 3)) << 4;   // pre-swizzled source col (bytes)
  const int lg = (lane >> 4) << 4;
  const int sw = (lane & 7) << 4;
  const int arow = (w << 6) + (lane & 15);
  const int brow = (lane & 15);
  f32x4 acc[4][4] = {};
  for (int s = 0; s < 64; ++s) {
    int k0 = (s & 31) << 6;
    const char* Ab; const char* B1b; const char* B2b = nullptr;
    if (s < 32) {
      Ab = (const char*)(xh + (size_t)row0 * HH + k0);
      B1b = (const char*)(UhT + (size_t)bidx * NUU + k0);
      B2b = (const char*)(UlT + (size_t)bidx * NUU + k0);
    } else {
      Ab = (const char*)(xl + (size_t)row0 * HH + k0);
      B1b = (const char*)(UhT + (size_t)bidx * NUU + k0);
    }
    const size_t stride = HH * 2;
#pragma unroll
    for (int i = 0; i < 8; ++i)
      GL16(Ab + (size_t)(srow + (i << 4)) * stride + scb, ldsA + (i << 11) + (w << 10));
#pragma unroll
    for (int i = 0; i < 4; ++i) {
      size_t go = (size_t)(srow + (i << 4)) * stride + scb;
      GL16(B1b + go, ldsB1 + (i << 11) + (w << 10));
      if (B2b) GL16(B2b + go, ldsB2 + (i << 11) + (w << 10));
    }
    __syncthreads();
#pragma unroll
    for (int ks = 0; ks < 2; ++ks) {
      const int cb = (ks << 6) + lg;
      short8v a_frag[4], b_frag[4];
#pragma unroll
      for (int mi = 0; mi < 4; ++mi)
        a_frag[mi] = *(const short8v*)(ldsA + ((arow + (mi << 4)) << 7) + (cb ^ sw));
#pragma unroll
      for (int ni = 0; ni < 4; ++ni)
        b_frag[ni] = *(const short8v*)(ldsB1 + ((brow + (ni << 4)) << 7) + (cb ^ sw));
#pragma unroll
      for (int mi = 0; mi < 4; ++mi)
#pragma unroll
        for (int ni = 0; ni < 4; ++ni)
          acc[mi][ni] = __builtin_amdgcn_mfma_f32_16x16x32_bf16(
              a_frag[mi], b_frag[ni], acc[mi][ni], 0, 0, 0);
      if (B2b) {
#pragma unroll
        for (int ni = 0; ni < 4; ++ni)
          b_frag[ni] = *(const short8v*)(ldsB2 + ((brow + (ni << 4)) << 7) + (cb ^ sw));
#pragma unroll
        for (int mi = 0; mi < 4; ++mi)
#pragma unroll
          for (int ni = 0; ni < 4; ++ni)
            acc[mi][ni] = __builtin_amdgcn_mfma_f32_16x16x32_bf16(
                a_frag[mi], b_frag[ni], acc[mi][ni], 0, 0, 0);
      }
    }
    __syncthreads();
  }
  const int crow = row0 + (w << 6) + ((lane >> 4) << 2);
  const int ccol = lane & 15;
#pragma unroll
  for (int mi = 0; mi < 4; ++mi)
#pragma unroll
    for (int ni = 0; ni < 4; ++ni)
#pragma unroll
      for (int j = 0; j < 4; ++j) {
        float v = acc[mi][ni][j];
        ushort_t hb = f2bf(v);
        size_t o = (size_t)(crow + (mi << 4) + j) * RR + ccol + (ni << 4);
        Ph[o] = hb;
        Pl[o] = f2bf(v - bf2f(hb));
      }
}

// ---------------- main MFMA GEMM, m97-style global_load_lds staging ----------------
// 128x128 tile, BK=64; A-reuse schedule: 32x {xh: Bh,Bl} + 32x {xl: Bh} + {Ph: Vh,Vl} + {Pl: Vh}
__global__ __launch_bounds__(256, 3) void gemm_mfma_kernel(
    const ushort_t* __restrict__ xh, const ushort_t* __restrict__ xl,
    const ushort_t* __restrict__ BhT, const ushort_t* __restrict__ BlT,
    const ushort_t* __restrict__ Ph, const ushort_t* __restrict__ Pl,
    const ushort_t* __restrict__ VhT, const ushort_t* __restrict__ VlT,
    float* __restrict__ out) {
  __shared__ __align__(16) char smem[49152];
  char* ldsA = smem;
  char* ldsB1 = smem + 16384;
  char* ldsB2 = smem + 32768;

  const int t = threadIdx.x;
  const int lane = t & 63;
  const int w = t >> 6;
  const int wr = w >> 1, wc = w & 1;

  // XCD-chunked block order: each XCD gets 256 consecutive wg = 2 col-panels x 128 row-panels
  int bid = blockIdx.x;
  int wg = ((bid & 7) << 8) | (bid >> 3);
  const int row0 = (wg & 127) << 7;
  const int n0 = (wg >> 7) << 7;
  const int bidx = row0 >> 12;

  const int srow = (w << 3) + (lane >> 3);
  const int scb = ((lane & 7) ^ (lane >> 3)) << 4;   // pre-swizzled source col (bytes)
  const int lg = (lane >> 4) << 4;
  const int sw = (lane & 7) << 4;
  const int arow = (wr << 6) + (lane & 15);
  const int brow = (wc << 6) + (lane & 15);

  f32x4 acc[4][4] = {};

  for (int s = 0; s < 66; ++s) {
    const char* Ab; const char* B1b; const char* B2b = nullptr;
    size_t stride;
    if (s < 32) {
      Ab  = (const char*)(xh + (size_t)row0 * HH + (s << 6));
      B1b = (const char*)(BhT + (size_t)n0 * HH + (s << 6));
      B2b = (const char*)(BlT + (size_t)n0 * HH + (s << 6));
      stride = HH * 2;
    } else if (s < 64) {
      Ab  = (const char*)(xl + (size_t)row0 * HH + ((s - 32) << 6));
      B1b = (const char*)(BhT + (size_t)n0 * HH + ((s - 32) << 6));
      stride = HH * 2;
    } else if (s == 64) {
      Ab  = (const char*)(Ph + (size_t)row0 * RR);
      B1b = (const char*)(VhT + (size_t)bidx * NUU + (size_t)n0 * RR);
      B2b = (const char*)(VlT + (size_t)bidx * NUU + (size_t)n0 * RR);
      stride = RR * 2;
    } else {
      Ab  = (const char*)(Pl + (size_t)row0 * RR);
      B1b = (const char*)(VhT + (size_t)bidx * NUU + (size_t)n0 * RR);
      stride = RR * 2;
    }
#pragma unroll
    for (int i = 0; i < 4; ++i) {
      size_t go = (size_t)(srow + (i << 5)) * stride + scb;
      GL16(Ab + go, ldsA + (i << 12) + (w << 10));
      GL16(B1b + go, ldsB1 + (i << 12) + (w << 10));
      if (B2b) GL16(B2b + go, ldsB2 + (i << 12) + (w << 10));
    }
    __syncthreads();   // compiler drains vmcnt before barrier -> tiles visible
#pragma unroll
    for (int ks = 0; ks < 2; ++ks) {
      const int cb = (ks << 6) + lg;
      short8v a_frag[4], b_frag[4];
#pragma unroll
      for (int mi = 0; mi < 4; ++mi)
        a_frag[mi] = *(const short8v*)(ldsA + ((arow + (mi << 4)) << 7) + (cb ^ sw));
#pragma unroll
      for (int ni = 0; ni < 4; ++ni)
        b_frag[ni] = *(const short8v*)(ldsB1 + ((brow + (ni << 4)) << 7) + (cb ^ sw));
#pragma unroll
      for (int mi = 0; mi < 4; ++mi)
#pragma unroll
        for (int ni = 0; ni < 4; ++ni)
          acc[mi][ni] = __builtin_amdgcn_mfma_f32_16x16x32_bf16(
              a_frag[mi], b_frag[ni], acc[mi][ni], 0, 0, 0);
      if (B2b) {
#pragma unroll
        for (int ni = 0; ni < 4; ++ni)
          b_frag[ni] = *(const short8v*)(ldsB2 + ((brow + (ni << 4)) << 7) + (cb ^ sw));
#pragma unroll
        for (int mi = 0; mi < 4; ++mi)
#pragma unroll
          for (int ni = 0; ni < 4; ++ni)
            acc[mi][ni] = __builtin_amdgcn_mfma_f32_16x16x32_bf16(
                a_frag[mi], b_frag[ni], acc[mi][ni], 0, 0, 0);
      }
    }
    __syncthreads();   // done reading before next stage overwrites
  }

  // C write (m89-verified layout), nontemporal to keep L2/L3 clean for A/B streams
  const int crow = row0 + (wr << 6) + ((lane >> 4) << 2);
  const int ccol = n0 + (wc << 6) + (lane & 15);
#pragma unroll
  for (int mi = 0; mi < 4; ++mi)
#pragma unroll
    for (int ni = 0; ni < 4; ++ni)
#pragma unroll
      for (int j = 0; j < 4; ++j)
        __builtin_nontemporal_store(
            acc[mi][ni][j],
            &out[(size_t)(crow + (mi << 4) + j) * HH + ccol + (ni << 4)]);
}

extern "C" void kernel_launch(void* const* d_in, const int* in_sizes, int n_in,
                              void* d_out, int out_size, void* d_ws, size_t ws_size,
                              hipStream_t stream) {
  const float* x = (const float*)d_in[0];
  const float* W1 = (const float*)d_in[1];
  const float* b1 = (const float*)d_in[2];
  const float* g1 = (const float*)d_in[3];
  const float* beta1 = (const float*)d_in[4];
  const float* W2 = (const float*)d_in[5];
  const float* b2 = (const float*)d_in[6];
  const float* g2 = (const float*)d_in[7];
  const float* beta2 = (const float*)d_in[8];
  const float* W3 = (const float*)d_in[9];
  const float* b3 = (const float*)d_in[10];
  const float* Wu = (const float*)d_in[11];
  const float* bu = (const float*)d_in[12];
  const float* Wv = (const float*)d_in[13];
  const float* bv = (const float*)d_in[14];
  const float* su = (const float*)d_in[15];
  const float* sv = (const float*)d_in[16];
  const float* rw = (const float*)d_in[17];
  const float* Bse = (const float*)d_in[18];
  float* out = (float*)d_out;

  char* w = (char*)d_ws;
  size_t off = 0;
  auto alloc = [&](size_t bytes) { char* p = w + off; off += (bytes + 255) & ~(size_t)255; return p; };

  float* norms = (float*)alloc((size_t)BB * SS * 4);
  float* zbuf  = (float*)alloc((size_t)BB * (N1 + N2 + N3) * 4);
  float* z1 = zbuf, *z2 = zbuf + BB * N1, *z3 = z2 + BB * N2;
  float* feats = (float*)alloc((size_t)BB * HF * 4);
  float* h1 = (float*)alloc((size_t)BB * N1 * 4);
  float* h2 = (float*)alloc((size_t)BB * N2 * 4);
  float* h3 = (float*)alloc((size_t)BB * N3 * 4);
  float* part = (float*)alloc((size_t)BB * NCHUNK * 6 * HH * 4);
  ushort_t* xh  = (ushort_t*)alloc((size_t)MM * HH * 2);
  ushort_t* xl  = (ushort_t*)alloc((size_t)MM * HH * 2);
  ushort_t* BhT = (ushort_t*)alloc((size_t)HH * HH * 2);
  ushort_t* BlT = (ushort_t*)alloc((size_t)HH * HH * 2);
  ushort_t* UhT = (ushort_t*)alloc((size_t)BB * NUU * 2);
  ushort_t* UlT = (ushort_t*)alloc((size_t)BB * NUU * 2);
  ushort_t* Phb = (ushort_t*)alloc((size_t)MM * RR * 2);
  ushort_t* Plb = (ushort_t*)alloc((size_t)MM * RR * 2);
  ushort_t* VhT = (ushort_t*)alloc((size_t)BB * NUU * 2);
  ushort_t* VlT = (ushort_t*)alloc((size_t)BB * NUU * 2);

  hipMemsetAsync(zbuf, 0, (size_t)BB * (N1 + N2 + N3) * sizeof(float), stream);

  // stats + conversions
  rownorm_kernel<<<BB * SS, 256, 0, stream>>>(x, norms);
  stats_convert_kernel<<<dim3(HH / 256, BB * NCHUNK), 256, 0, stream>>>(x, part, xh, xl);
  moment_reduce_kernel<<<dim3(HH / 256, BB), 256, 0, stream>>>(part, feats);
  nrm_reduce_kernel<<<BB, 256, 0, stream>>>(norms, feats);
  convert_base_kernel<<<dim3(HH / 64, HH / 64), 256, 0, stream>>>(Bse, rw, BhT, BlT);

  // MLP
  gemm_small_kernel<<<dim3(HF / 512, N1 / 256), 256, 4 * 512 * sizeof(float), stream>>>(
      feats, W1, z1, HF, N1, 512);
  ln_relu_kernel<<<BB, 256, 0, stream>>>(z1, b1, g1, beta1, h1, N1);
  gemm_small_kernel<<<dim3(N1 / 512, N2 / 256), 256, 4 * 512 * sizeof(float), stream>>>(
      h1, W2, z2, N1, N2, 512);
  ln_relu_kernel<<<BB, 256, 0, stream>>>(z2, b2, g2, beta2, h2, N2);
  gemm_small_kernel<<<dim3(N2 / 256, N3 / 256), 256, 4 * 256 * sizeof(float), stream>>>(
      h2, W3, z3, N2, N3, 256);
  bias_relu3_kernel<<<1, 256, 0, stream>>>(z3, b3, h3);

  // U^T/V^T bf16 splits
  uv_kernel<<<dim3(NUU / 256, 2), 256, 0, stream>>>(h3, Wu, bu, su, Wv, bv, sv, rw,
                                                    UhT, UlT, VhT, VlT);

  // P = x @ U via MFMA -> bf16 splits
  p_mfma_kernel<<<MM / 128, 128, 0, stream>>>(xh, xl, UhT, UlT, Phb, Plb);

  // fused: out = rw*x@Base + (1-rw)*(x@U)@V
  gemm_mfma_kernel<<<MM / 128 * (HH / 128), 256, 0, stream>>>(
      xh, xl, BhT, BlT, Phb, Plb, VhT, VlT, out);
}